// Round 13
// baseline (106.002 us; speedup 1.0000x reference)
//
#include <hip/hip_runtime.h>
#include <hip/hip_fp16.h>

// Radon forward: x [4,1,256,256] f32, thetas[180], positions[256] -> out [4,1,180,256] f32
// T=363 samples/ray (run 364; extras land in the zero border -> +0).
//
// Round 13 = round-12 kernel (best: 51.9us) + explicit dual-stream ILP in the
// ray integral (2 independent acc/px/py streams, interleaved t, unroll 2 ->
// 4 independent samples in flight; the round-12 chain addr->ds->shift->lerp
// was latency-bound at ~33% per-SIMD VALU issue) + fract/cvt/mad_u24 addressing.

#define NB   4
#define NA   180
#define NP   256
#define GANG 3       // angles per block; regime boundaries 45,135 are multiples of 3
#define IMG_DW_MAX 17353
#define SMEM_BYTES ((IMG_DW_MAX + 1) * 4)   // 69416 B; x2 blocks = 139KB <= 160KB/CU

__device__ __forceinline__ unsigned pack_h2(float a, float b) {
    __half2 h = __halves2half2(__float2half_rn(a), __float2half_rn(b));
    return *reinterpret_cast<unsigned*>(&h);
}

template<int STRIDE_DW>
__device__ __forceinline__ void sample_one(
    const unsigned int* __restrict__ imgw, float px, float py, float& acc)
{
    const float wx = __builtin_amdgcn_fractf(px);
    const float wy = __builtin_amdgcn_fractf(py);
    const int ix = (int)px;                         // px >= 0 after clamp
    const int iy = (int)py;
    const int a  = iy * (2 * STRIDE_DW) + ix;       // < 2^17 -> mad_u24
    const int kd = a >> 1;
    const unsigned sh = (a & 1) << 4;
    const unsigned d0 = imgw[kd];
    const unsigned d1 = imgw[kd + 1];
    const unsigned d2 = imgw[kd + STRIDE_DW];
    const unsigned d3 = imgw[kd + STRIDE_DW + 1];
    unsigned q0 = (unsigned)(((((unsigned long long)d1) << 32) | d0) >> sh);
    unsigned q1 = (unsigned)(((((unsigned long long)d3) << 32) | d2) >> sh);
    const __half2 h0 = *reinterpret_cast<__half2*>(&q0);   // (v00, v01)
    const __half2 h1 = *reinterpret_cast<__half2*>(&q1);   // (v10, v11)
    const __half2 wy2 = __half2half2(__float2half_rn(wy));
    const __half2 V   = __hfma2(wy2, __hsub2(h1, h0), h0); // vertical lerp
    const float vlo = __half2float(__low2half(V));
    const float vhi = __half2float(__high2half(V));
    acc = fmaf(wx, vhi - vlo, acc + vlo);
}

template<int STRIDE_DW>
__device__ __forceinline__ float ray_accum(
    const unsigned int* __restrict__ imgw,
    float bxr, float byr, float nsv, float cv,
    float xlo, float xhi, float ylo, float yhi,
    int tlo, int thi, int seg)
{
    int t = tlo + seg;
    float accA = 0.f, accB = 0.f;
    // stream A: t, t+8, ... ; stream B: t+4, t+12, ...
    float pxA = fmaf((float)t - 181.0f, nsv, bxr);
    float pyA = fmaf((float)t - 181.0f, cv,  byr);
    float pxB = fmaf(4.0f, nsv, pxA);
    float pyB = fmaf(4.0f, cv,  pyA);
    const float dpx = 8.0f * nsv;
    const float dpy = 8.0f * cv;
    #pragma unroll 2
    for (; t + 4 < thi; t += 8) {
        sample_one<STRIDE_DW>(imgw,
            __builtin_amdgcn_fmed3f(pxA, xlo, xhi),
            __builtin_amdgcn_fmed3f(pyA, ylo, yhi), accA);
        sample_one<STRIDE_DW>(imgw,
            __builtin_amdgcn_fmed3f(pxB, xlo, xhi),
            __builtin_amdgcn_fmed3f(pyB, ylo, yhi), accB);
        pxA += dpx; pyA += dpy;
        pxB += dpx; pyB += dpy;
    }
    if (t < thi) {
        sample_one<STRIDE_DW>(imgw,
            __builtin_amdgcn_fmed3f(pxA, xlo, xhi),
            __builtin_amdgcn_fmed3f(pyA, ylo, yhi), accA);
    }
    return accA + accB;
}

extern "C" __global__ __launch_bounds__(1024)
void radon_fwd(const float* __restrict__ x,
               const float* __restrict__ thetas,
               const float* __restrict__ positions,
               float* __restrict__ out)
{
    extern __shared__ unsigned char smem[];
    unsigned int* imgw = (unsigned int*)smem;

    const int grp  = blockIdx.x;
    const int b    = blockIdx.y;
    const int half = blockIdx.z;
    const int a0   = grp * GANG;
    const bool regA = (a0 < 45) || (a0 >= 135);
    const int tid = threadIdx.x;                 // 0..1023
    const float* __restrict__ xb = x + b * 65536;

    // --- zero LDS image area (borders) ---
    for (int i = tid; i <= IMG_DW_MAX; i += 1024) imgw[i] = 0u;
    __syncthreads();

    // --- stage half image as f16 half2 (round-8 proven layout) ---
    if (regA) {
        // half0: img rows 0..129 -> lds rows 1..130 ; half1: img rows 126..255 -> lds rows 0..129
        const int rbase  = half ? 126 : 0;
        const int rowoff = half ? 0 : 1;
        const float2* src2 = (const float2*)(xb + rbase * 256);
        for (int j = tid; j < 130 * 128; j += 1024) {
            const int rr = j >> 7;         // 0..129
            const int k  = j & 127;        // float2 index within row
            float2 v = src2[rr * 128 + k];
            imgw[(rr + rowoff) * 131 + k + 1] = pack_h2(v.x, v.y);
        }
    } else {
        // half0: img cols 0..131 -> lds dw cols 1..66 ; half1: img cols 124..255 -> dw cols 0..65
        const int cbase2 = half ? 62 : 0;
        const int coff   = half ? 0 : 1;
        const float2* src2 = (const float2*)xb;
        for (int rr = tid >> 6; rr < 256; rr += 16) {
            for (int c2 = tid & 63; c2 < 66; c2 += 64) {
                float2 v = src2[rr * 128 + cbase2 + c2];
                imgw[(rr + 1) * 67 + c2 + coff] = pack_h2(v.x, v.y);
            }
        }
    }
    __syncthreads();

    // --- per-half clamp bounds (alloc space, rebased) ---
    float xlo, xhi, ylo, yhi;
    if (regA) {
        xlo = 1.f; xhi = 258.f;
        if (half == 0) { ylo = 0.f; yhi = 129.984375f; }
        else           { ylo = 1.f; yhi = 130.f; }
    } else {
        ylo = 0.f; yhi = 257.f;
        if (half == 0) { xlo = 1.f; xhi = 130.984375f; }
        else           { xlo = 3.f; xhi = 132.f; }
    }
    const float rebY = (regA && half) ? 127.f : 0.f;
    const float rebX = (!regA && half) ? 126.f : 0.f;

    // --- quad mapping: 4 segs of one ray in adjacent lanes (round-12 win) ---
    const int lane = tid & 63;
    const int seg  = lane & 3;
    const int p    = ((tid >> 6) << 4) + (lane >> 2);   // 0..255
    const float s  = positions[p];

    for (int g = 0; g < GANG; ++g) {
        const float th  = thetas[a0 + g];
        const float cv  = cosf(th);
        const float sv  = sinf(th);
        const float nsv = -sv;
        const float bx2 = fmaf(s, cv, 129.5f);   // alloc-x base (col offset +2)
        const float by1 = fmaf(s, sv, 128.5f);   // alloc-y base (row offset +1)
        // ownership split: alloc(t) = base + (t-181)*slope => t* = 181 + (thr-base)/slope
        const float slope = regA ? cv : nsv;     // |slope| >= 0.707 by regime choice
        const float base  = regA ? by1 : bx2;
        const float thr   = regA ? 129.f : 130.f;
        const float tstar = 181.0f + (thr - base) / slope;
        const float Sf    = (slope > 0.f) ? ceilf(tstar) : (floorf(tstar) + 1.0f);
        const int   S     = (int)fmaxf(0.f, fminf(364.f, Sf));
        const bool  h0Low = (slope > 0.f);
        const int lo = ((half == 0) == h0Low) ? 0 : S;
        const int hi = ((half == 0) == h0Low) ? S : 364;

        // support clip (over-wide by 1 each side: skipped samples contribute 0)
        const float msx = (fabsf(sv) < 1e-7f) ? copysignf(1e-7f, sv) : sv;
        const float mcy = (fabsf(cv) < 1e-7f) ? copysignf(1e-7f, cv) : cv;
        const float invx = -1.0f / msx;
        const float invy =  1.0f / mcy;
        const float ux1 = (1.0f   - bx2) * invx;
        const float ux2 = (258.0f - bx2) * invx;
        const float uy1 = (0.0f   - by1) * invy;
        const float uy2 = (257.0f - by1) * invy;
        const float ulo = fmaxf(fminf(ux1, ux2), fminf(uy1, uy2));
        const float uhi = fminf(fmaxf(ux1, ux2), fmaxf(uy1, uy2));
        const float tbf = ceilf(ulo + 181.0f) - 1.0f;
        const float tef = floorf(uhi + 181.0f) + 2.0f;
        const int tb = (int)fmaxf((float)lo, fminf(364.0f, tbf));
        const int te = (int)fminf((float)hi, fmaxf(0.0f,  tef));

        const float bxr = bx2 - rebX;
        const float byr = by1 - rebY;
        float acc = regA
            ? ray_accum<131>(imgw, bxr, byr, nsv, cv, xlo, xhi, ylo, yhi, tb, te, seg)
            : ray_accum< 67>(imgw, bxr, byr, nsv, cv, xlo, xhi, ylo, yhi, tb, te, seg);

        // 4-seg reduction within the lane quad (deterministic butterfly)
        acc += __shfl_xor(acc, 1, 64);
        acc += __shfl_xor(acc, 2, 64);
        if (seg == 0)
            atomicAdd(&out[b * (NA * NP) + (a0 + g) * NP + p], acc);
    }
}

extern "C" void kernel_launch(void* const* d_in, const int* in_sizes, int n_in,
                              void* d_out, int out_size, void* d_ws, size_t ws_size,
                              hipStream_t stream) {
    const float* x         = (const float*)d_in[0];
    const float* thetas    = (const float*)d_in[1];
    const float* positions = (const float*)d_in[2];
    float* out = (float*)d_out;

    hipFuncSetAttribute((const void*)radon_fwd,
                        hipFuncAttributeMaxDynamicSharedMemorySize, SMEM_BYTES);

    // output accumulated via atomics -> zero it first (async, capture-safe)
    hipMemsetAsync(d_out, 0, (size_t)out_size * sizeof(float), stream);

    dim3 grid(NA / GANG, NB, 2);   // 60 x 4 x 2 = 480 blocks
    dim3 block(1024);              // 16 waves; lane quad = 4 segs of one ray
    radon_fwd<<<grid, block, SMEM_BYTES, stream>>>(x, thetas, positions, out);
}

// Round 14
// 104.224 us; speedup vs baseline: 1.0171x; 1.0171x over previous
//
#include <hip/hip_runtime.h>
#include <hip/hip_fp16.h>

// Radon forward: x [4,1,256,256] f32, thetas[180], positions[256] -> out [4,1,180,256] f32
// T=363 samples/ray (run 364; extras land in the zero border -> +0).
//
// Round 14 = round-12 kernel (best: 51.9us) + __launch_bounds__(1024, 8).
// Rationale: dynamic LDS (69.4KB x2 blocks/CU) caps occupancy at 8 waves/EU,
// but the compiler can't see dynamic LDS and was allocating for 16 waves/EU
// (VGPR=32), strangling ILP in the unroll-4 sample pipeline. Declaring 8
// waves/EU raises the register budget to 64, letting the compiler keep 4
// independent samples in flight (addr -> 2x ds_read2 -> funnel-shift -> lerp).

#define NB   4
#define NA   180
#define NP   256
#define GANG 3       // angles per block; regime boundaries 45,135 are multiples of 3
#define IMG_DW_MAX 17353
#define SMEM_BYTES ((IMG_DW_MAX + 1) * 4)   // 69416 B; x2 blocks = 139KB <= 160KB/CU

__device__ __forceinline__ unsigned pack_h2(float a, float b) {
    __half2 h = __halves2half2(__float2half_rn(a), __float2half_rn(b));
    return *reinterpret_cast<unsigned*>(&h);
}

template<int STRIDE_DW>
__device__ __forceinline__ float ray_accum(
    const unsigned int* __restrict__ imgw,
    float bxr, float byr, float nsv, float cv,
    float xlo, float xhi, float ylo, float yhi,
    int tlo, int thi, int seg)
{
    float acc = 0.f;
    int   t  = tlo + seg;
    float pxu = fmaf((float)t - 181.0f, nsv, bxr);
    float pyu = fmaf((float)t - 181.0f, cv,  byr);
    const float dpx = 4.0f * nsv;
    const float dpy = 4.0f * cv;
    #pragma unroll 4
    for (; t < thi; t += 4) {
        float px = __builtin_amdgcn_fmed3f(pxu, xlo, xhi);
        float py = __builtin_amdgcn_fmed3f(pyu, ylo, yhi);
        pxu += dpx;
        pyu += dpy;
        const float fx = floorf(px);
        const float fy = floorf(py);
        const float wx = px - fx;
        const float wy = py - fy;
        const int a  = (int)fmaf(fy, (float)(2 * STRIDE_DW), fx);  // half-index
        const int kd = a >> 1;
        const unsigned sh = (a & 1) << 4;
        const unsigned d0 = imgw[kd];
        const unsigned d1 = imgw[kd + 1];
        const unsigned d2 = imgw[kd + STRIDE_DW];
        const unsigned d3 = imgw[kd + STRIDE_DW + 1];
        unsigned q0 = (unsigned)(((((unsigned long long)d1) << 32) | d0) >> sh);
        unsigned q1 = (unsigned)(((((unsigned long long)d3) << 32) | d2) >> sh);
        const __half2 h0 = *reinterpret_cast<__half2*>(&q0);   // (v00, v01)
        const __half2 h1 = *reinterpret_cast<__half2*>(&q1);   // (v10, v11)
        const __half2 dv  = __hsub2(h1, h0);
        const __half2 wy2 = __half2half2(__float2half_rn(wy));
        const __half2 V   = __hfma2(wy2, dv, h0);
        const float vlo = __half2float(__low2half(V));
        const float vhi = __half2float(__high2half(V));
        acc = fmaf(wx, vhi - vlo, acc + vlo);
    }
    return acc;
}

extern "C" __global__ __launch_bounds__(1024, 8)
void radon_fwd(const float* __restrict__ x,
               const float* __restrict__ thetas,
               const float* __restrict__ positions,
               float* __restrict__ out)
{
    extern __shared__ unsigned char smem[];
    unsigned int* imgw = (unsigned int*)smem;

    const int grp  = blockIdx.x;
    const int b    = blockIdx.y;
    const int half = blockIdx.z;
    const int a0   = grp * GANG;
    const bool regA = (a0 < 45) || (a0 >= 135);
    const int tid = threadIdx.x;                 // 0..1023
    const float* __restrict__ xb = x + b * 65536;

    // --- zero LDS image area (borders) ---
    for (int i = tid; i <= IMG_DW_MAX; i += 1024) imgw[i] = 0u;
    __syncthreads();

    // --- stage half image as f16 half2 (round-8 proven layout) ---
    if (regA) {
        // half0: img rows 0..129 -> lds rows 1..130 ; half1: img rows 126..255 -> lds rows 0..129
        const int rbase  = half ? 126 : 0;
        const int rowoff = half ? 0 : 1;
        const float2* src2 = (const float2*)(xb + rbase * 256);
        for (int j = tid; j < 130 * 128; j += 1024) {
            const int rr = j >> 7;         // 0..129
            const int k  = j & 127;        // float2 index within row
            float2 v = src2[rr * 128 + k];
            imgw[(rr + rowoff) * 131 + k + 1] = pack_h2(v.x, v.y);
        }
    } else {
        // half0: img cols 0..131 -> lds dw cols 1..66 ; half1: img cols 124..255 -> dw cols 0..65
        const int cbase2 = half ? 62 : 0;
        const int coff   = half ? 0 : 1;
        const float2* src2 = (const float2*)xb;
        for (int rr = tid >> 6; rr < 256; rr += 16) {
            for (int c2 = tid & 63; c2 < 66; c2 += 64) {
                float2 v = src2[rr * 128 + cbase2 + c2];
                imgw[(rr + 1) * 67 + c2 + coff] = pack_h2(v.x, v.y);
            }
        }
    }
    __syncthreads();

    // --- per-half clamp bounds (alloc space, rebased) ---
    float xlo, xhi, ylo, yhi;
    if (regA) {
        xlo = 1.f; xhi = 258.f;
        if (half == 0) { ylo = 0.f; yhi = 129.984375f; }
        else           { ylo = 1.f; yhi = 130.f; }
    } else {
        ylo = 0.f; yhi = 257.f;
        if (half == 0) { xlo = 1.f; xhi = 130.984375f; }
        else           { xlo = 3.f; xhi = 132.f; }
    }
    const float rebY = (regA && half) ? 127.f : 0.f;
    const float rebX = (!regA && half) ? 126.f : 0.f;

    // --- quad mapping: 4 segs of one ray in adjacent lanes (round-12 win) ---
    const int lane = tid & 63;
    const int seg  = lane & 3;
    const int p    = ((tid >> 6) << 4) + (lane >> 2);   // 0..255
    const float s  = positions[p];

    for (int g = 0; g < GANG; ++g) {
        const float th  = thetas[a0 + g];
        const float cv  = cosf(th);
        const float sv  = sinf(th);
        const float nsv = -sv;
        const float bx2 = fmaf(s, cv, 129.5f);   // alloc-x base (col offset +2)
        const float by1 = fmaf(s, sv, 128.5f);   // alloc-y base (row offset +1)
        // ownership split: alloc(t) = base + (t-181)*slope => t* = 181 + (thr-base)/slope
        const float slope = regA ? cv : nsv;     // |slope| >= 0.707 by regime choice
        const float base  = regA ? by1 : bx2;
        const float thr   = regA ? 129.f : 130.f;
        const float tstar = 181.0f + (thr - base) / slope;
        const float Sf    = (slope > 0.f) ? ceilf(tstar) : (floorf(tstar) + 1.0f);
        const int   S     = (int)fmaxf(0.f, fminf(364.f, Sf));
        const bool  h0Low = (slope > 0.f);
        const int lo = ((half == 0) == h0Low) ? 0 : S;
        const int hi = ((half == 0) == h0Low) ? S : 364;

        // support clip (over-wide by 1 each side: skipped samples contribute 0)
        const float msx = (fabsf(sv) < 1e-7f) ? copysignf(1e-7f, sv) : sv;
        const float mcy = (fabsf(cv) < 1e-7f) ? copysignf(1e-7f, cv) : cv;
        const float invx = -1.0f / msx;
        const float invy =  1.0f / mcy;
        const float ux1 = (1.0f   - bx2) * invx;
        const float ux2 = (258.0f - bx2) * invx;
        const float uy1 = (0.0f   - by1) * invy;
        const float uy2 = (257.0f - by1) * invy;
        const float ulo = fmaxf(fminf(ux1, ux2), fminf(uy1, uy2));
        const float uhi = fminf(fmaxf(ux1, ux2), fmaxf(uy1, uy2));
        const float tbf = ceilf(ulo + 181.0f) - 1.0f;
        const float tef = floorf(uhi + 181.0f) + 2.0f;
        const int tb = (int)fmaxf((float)lo, fminf(364.0f, tbf));
        const int te = (int)fminf((float)hi, fmaxf(0.0f,  tef));

        const float bxr = bx2 - rebX;
        const float byr = by1 - rebY;
        float acc = regA
            ? ray_accum<131>(imgw, bxr, byr, nsv, cv, xlo, xhi, ylo, yhi, tb, te, seg)
            : ray_accum< 67>(imgw, bxr, byr, nsv, cv, xlo, xhi, ylo, yhi, tb, te, seg);

        // 4-seg reduction within the lane quad (deterministic butterfly)
        acc += __shfl_xor(acc, 1, 64);
        acc += __shfl_xor(acc, 2, 64);
        if (seg == 0)
            atomicAdd(&out[b * (NA * NP) + (a0 + g) * NP + p], acc);
    }
}

extern "C" void kernel_launch(void* const* d_in, const int* in_sizes, int n_in,
                              void* d_out, int out_size, void* d_ws, size_t ws_size,
                              hipStream_t stream) {
    const float* x         = (const float*)d_in[0];
    const float* thetas    = (const float*)d_in[1];
    const float* positions = (const float*)d_in[2];
    float* out = (float*)d_out;

    hipFuncSetAttribute((const void*)radon_fwd,
                        hipFuncAttributeMaxDynamicSharedMemorySize, SMEM_BYTES);

    // output accumulated via atomics -> zero it first (async, capture-safe)
    hipMemsetAsync(d_out, 0, (size_t)out_size * sizeof(float), stream);

    dim3 grid(NA / GANG, NB, 2);   // 60 x 4 x 2 = 480 blocks
    dim3 block(1024);              // 16 waves; lane quad = 4 segs of one ray
    radon_fwd<<<grid, block, SMEM_BYTES, stream>>>(x, thetas, positions, out);
}

// Round 15
// 103.260 us; speedup vs baseline: 1.0266x; 1.0093x over previous
//
#include <hip/hip_runtime.h>
#include <hip/hip_fp16.h>

// Radon forward: x [4,1,256,256] f32, thetas[180], positions[256] -> out [4,1,180,256] f32
// T=363 samples/ray (run 364; extras land in the zero border -> +0).
//
// Round 15 = round-12 kernel (best: 51.9us) + HAND software pipeline in
// ray_accum: next sample's 4 LDS dwords are loaded BEFORE current sample's
// compute in program order (state rotated through locals, unroll 2). The
// compiler would not do this across iterations itself (VGPR stuck at 32,
// rounds 13/14) -> load-to-use distance was ~0 and the kernel ran
// latency-bound at ~40% per-pipe utilization.

#define NB   4
#define NA   180
#define NP   256
#define GANG 3       // angles per block; regime boundaries 45,135 are multiples of 3
#define IMG_DW_MAX 17353
#define SMEM_BYTES ((IMG_DW_MAX + 1) * 4)   // 69416 B; x2 blocks = 139KB <= 160KB/CU

__device__ __forceinline__ unsigned pack_h2(float a, float b) {
    __half2 h = __halves2half2(__float2half_rn(a), __float2half_rn(b));
    return *reinterpret_cast<unsigned*>(&h);
}

// current-sample bilinear from rotated state (bit-identical math to round 12)
__device__ __forceinline__ void bilerp_acc(
    unsigned d0, unsigned d1, unsigned d2, unsigned d3,
    unsigned sh, float wx, float wy, float& acc)
{
    unsigned q0 = (unsigned)(((((unsigned long long)d1) << 32) | d0) >> sh);
    unsigned q1 = (unsigned)(((((unsigned long long)d3) << 32) | d2) >> sh);
    const __half2 h0 = *reinterpret_cast<__half2*>(&q0);   // (v00, v01)
    const __half2 h1 = *reinterpret_cast<__half2*>(&q1);   // (v10, v11)
    const __half2 dv  = __hsub2(h1, h0);
    const __half2 wy2 = __half2half2(__float2half_rn(wy));
    const __half2 V   = __hfma2(wy2, dv, h0);
    const float vlo = __half2float(__low2half(V));
    const float vhi = __half2float(__high2half(V));
    acc = fmaf(wx, vhi - vlo, acc + vlo);
}

template<int STRIDE_DW>
__device__ __forceinline__ float ray_accum(
    const unsigned int* __restrict__ imgw,
    float bxr, float byr, float nsv, float cv,
    float xlo, float xhi, float ylo, float yhi,
    int tlo, int thi, int seg)
{
    int t = tlo + seg;
    if (t >= thi) return 0.f;
    float pxu = fmaf((float)t - 181.0f, nsv, bxr);
    float pyu = fmaf((float)t - 181.0f, cv,  byr);
    const float dpx = 4.0f * nsv;
    const float dpy = 4.0f * cv;

    // prologue: sample 0 address + loads
    float px = __builtin_amdgcn_fmed3f(pxu, xlo, xhi);
    float py = __builtin_amdgcn_fmed3f(pyu, ylo, yhi);
    float fx = floorf(px), fy = floorf(py);
    float wx = px - fx, wy = py - fy;
    int   a  = (int)fmaf(fy, (float)(2 * STRIDE_DW), fx);
    int   kd = a >> 1;
    unsigned sh = (a & 1) << 4;
    unsigned d0 = imgw[kd];
    unsigned d1 = imgw[kd + 1];
    unsigned d2 = imgw[kd + STRIDE_DW];
    unsigned d3 = imgw[kd + STRIDE_DW + 1];

    float acc = 0.f;
    #pragma unroll 2
    for (t += 4; t < thi; t += 4) {
        pxu += dpx; pyu += dpy;
        // ---- issue NEXT sample's loads first (program order = overlap) ----
        const float npx = __builtin_amdgcn_fmed3f(pxu, xlo, xhi);
        const float npy = __builtin_amdgcn_fmed3f(pyu, ylo, yhi);
        const float nfx = floorf(npx), nfy = floorf(npy);
        const float nwx = npx - nfx, nwy = npy - nfy;
        const int   na  = (int)fmaf(nfy, (float)(2 * STRIDE_DW), nfx);
        const int   nkd = na >> 1;
        const unsigned nsh = (na & 1) << 4;
        const unsigned nd0 = imgw[nkd];
        const unsigned nd1 = imgw[nkd + 1];
        const unsigned nd2 = imgw[nkd + STRIDE_DW];
        const unsigned nd3 = imgw[nkd + STRIDE_DW + 1];
        // ---- compute CURRENT sample ----
        bilerp_acc(d0, d1, d2, d3, sh, wx, wy, acc);
        // ---- rotate ----
        wx = nwx; wy = nwy; sh = nsh;
        d0 = nd0; d1 = nd1; d2 = nd2; d3 = nd3;
    }
    // epilogue: last sample
    bilerp_acc(d0, d1, d2, d3, sh, wx, wy, acc);
    return acc;
}

extern "C" __global__ __launch_bounds__(1024, 8)
void radon_fwd(const float* __restrict__ x,
               const float* __restrict__ thetas,
               const float* __restrict__ positions,
               float* __restrict__ out)
{
    extern __shared__ unsigned char smem[];
    unsigned int* imgw = (unsigned int*)smem;

    const int grp  = blockIdx.x;
    const int b    = blockIdx.y;
    const int half = blockIdx.z;
    const int a0   = grp * GANG;
    const bool regA = (a0 < 45) || (a0 >= 135);
    const int tid = threadIdx.x;                 // 0..1023
    const float* __restrict__ xb = x + b * 65536;

    // --- zero LDS image area (borders) ---
    for (int i = tid; i <= IMG_DW_MAX; i += 1024) imgw[i] = 0u;
    __syncthreads();

    // --- stage half image as f16 half2 (round-8 proven layout) ---
    if (regA) {
        // half0: img rows 0..129 -> lds rows 1..130 ; half1: img rows 126..255 -> lds rows 0..129
        const int rbase  = half ? 126 : 0;
        const int rowoff = half ? 0 : 1;
        const float2* src2 = (const float2*)(xb + rbase * 256);
        for (int j = tid; j < 130 * 128; j += 1024) {
            const int rr = j >> 7;         // 0..129
            const int k  = j & 127;        // float2 index within row
            float2 v = src2[rr * 128 + k];
            imgw[(rr + rowoff) * 131 + k + 1] = pack_h2(v.x, v.y);
        }
    } else {
        // half0: img cols 0..131 -> lds dw cols 1..66 ; half1: img cols 124..255 -> dw cols 0..65
        const int cbase2 = half ? 62 : 0;
        const int coff   = half ? 0 : 1;
        const float2* src2 = (const float2*)xb;
        for (int rr = tid >> 6; rr < 256; rr += 16) {
            for (int c2 = tid & 63; c2 < 66; c2 += 64) {
                float2 v = src2[rr * 128 + cbase2 + c2];
                imgw[(rr + 1) * 67 + c2 + coff] = pack_h2(v.x, v.y);
            }
        }
    }
    __syncthreads();

    // --- per-half clamp bounds (alloc space, rebased) ---
    float xlo, xhi, ylo, yhi;
    if (regA) {
        xlo = 1.f; xhi = 258.f;
        if (half == 0) { ylo = 0.f; yhi = 129.984375f; }
        else           { ylo = 1.f; yhi = 130.f; }
    } else {
        ylo = 0.f; yhi = 257.f;
        if (half == 0) { xlo = 1.f; xhi = 130.984375f; }
        else           { xlo = 3.f; xhi = 132.f; }
    }
    const float rebY = (regA && half) ? 127.f : 0.f;
    const float rebX = (!regA && half) ? 126.f : 0.f;

    // --- quad mapping: 4 segs of one ray in adjacent lanes (round-12 win) ---
    const int lane = tid & 63;
    const int seg  = lane & 3;
    const int p    = ((tid >> 6) << 4) + (lane >> 2);   // 0..255
    const float s  = positions[p];

    for (int g = 0; g < GANG; ++g) {
        const float th  = thetas[a0 + g];
        const float cv  = cosf(th);
        const float sv  = sinf(th);
        const float nsv = -sv;
        const float bx2 = fmaf(s, cv, 129.5f);   // alloc-x base (col offset +2)
        const float by1 = fmaf(s, sv, 128.5f);   // alloc-y base (row offset +1)
        // ownership split: alloc(t) = base + (t-181)*slope => t* = 181 + (thr-base)/slope
        const float slope = regA ? cv : nsv;     // |slope| >= 0.707 by regime choice
        const float base  = regA ? by1 : bx2;
        const float thr   = regA ? 129.f : 130.f;
        const float tstar = 181.0f + (thr - base) / slope;
        const float Sf    = (slope > 0.f) ? ceilf(tstar) : (floorf(tstar) + 1.0f);
        const int   S     = (int)fmaxf(0.f, fminf(364.f, Sf));
        const bool  h0Low = (slope > 0.f);
        const int lo = ((half == 0) == h0Low) ? 0 : S;
        const int hi = ((half == 0) == h0Low) ? S : 364;

        // support clip (over-wide by 1 each side: skipped samples contribute 0)
        const float msx = (fabsf(sv) < 1e-7f) ? copysignf(1e-7f, sv) : sv;
        const float mcy = (fabsf(cv) < 1e-7f) ? copysignf(1e-7f, cv) : cv;
        const float invx = -1.0f / msx;
        const float invy =  1.0f / mcy;
        const float ux1 = (1.0f   - bx2) * invx;
        const float ux2 = (258.0f - bx2) * invx;
        const float uy1 = (0.0f   - by1) * invy;
        const float uy2 = (257.0f - by1) * invy;
        const float ulo = fmaxf(fminf(ux1, ux2), fminf(uy1, uy2));
        const float uhi = fminf(fmaxf(ux1, ux2), fmaxf(uy1, uy2));
        const float tbf = ceilf(ulo + 181.0f) - 1.0f;
        const float tef = floorf(uhi + 181.0f) + 2.0f;
        const int tb = (int)fmaxf((float)lo, fminf(364.0f, tbf));
        const int te = (int)fminf((float)hi, fmaxf(0.0f,  tef));

        const float bxr = bx2 - rebX;
        const float byr = by1 - rebY;
        float acc = regA
            ? ray_accum<131>(imgw, bxr, byr, nsv, cv, xlo, xhi, ylo, yhi, tb, te, seg)
            : ray_accum< 67>(imgw, bxr, byr, nsv, cv, xlo, xhi, ylo, yhi, tb, te, seg);

        // 4-seg reduction within the lane quad (deterministic butterfly)
        acc += __shfl_xor(acc, 1, 64);
        acc += __shfl_xor(acc, 2, 64);
        if (seg == 0)
            atomicAdd(&out[b * (NA * NP) + (a0 + g) * NP + p], acc);
    }
}

extern "C" void kernel_launch(void* const* d_in, const int* in_sizes, int n_in,
                              void* d_out, int out_size, void* d_ws, size_t ws_size,
                              hipStream_t stream) {
    const float* x         = (const float*)d_in[0];
    const float* thetas    = (const float*)d_in[1];
    const float* positions = (const float*)d_in[2];
    float* out = (float*)d_out;

    hipFuncSetAttribute((const void*)radon_fwd,
                        hipFuncAttributeMaxDynamicSharedMemorySize, SMEM_BYTES);

    // output accumulated via atomics -> zero it first (async, capture-safe)
    hipMemsetAsync(d_out, 0, (size_t)out_size * sizeof(float), stream);

    dim3 grid(NA / GANG, NB, 2);   // 60 x 4 x 2 = 480 blocks
    dim3 block(1024);              // 16 waves; lane quad = 4 segs of one ray
    radon_fwd<<<grid, block, SMEM_BYTES, stream>>>(x, thetas, positions, out);
}